// Round 15
// baseline (314.579 us; speedup 1.0000x reference)
//
#include <hip/hip_runtime.h>
#include <hip/hip_bf16.h>

typedef unsigned int u32;
typedef unsigned short u16;

__device__ __forceinline__ u16 f2bf(float f){ u32 x; __builtin_memcpy(&x,&f,4); u32 r=(x+0x7fffu+((x>>16)&1u))>>16; return (u16)r; }

// ---------------- K0: transpose x (32 x 4096) -> xt (4096 x 32) ----------------
__global__ __launch_bounds__(256) void transpose_x(
    const float* __restrict__ x, float* __restrict__ xt)
{
    __shared__ float ld[32][65];
    const int t = threadIdx.x;
    const int g = blockIdx.x;
    #pragma unroll
    for (int i=0;i<8;++i) {
        const int e = i*256 + t;
        const int b = e >> 6, dd = e & 63;
        ld[b][dd] = x[(size_t)b*4096 + g*64 + dd];
    }
    __syncthreads();
    #pragma unroll
    for (int i=0;i<8;++i) {
        const int e = i*256 + t;
        const int dd = e >> 5, b = e & 31;
        xt[(size_t)(g*64 + dd)*32 + b] = ld[b][dd];
    }
}

// ---------------- K1/K3: split-K GEMM with transposed A: (K x 32) ----------------
__global__ __launch_bounds__(256) void gemm_splitk_t(
    const float* __restrict__ At, const float2* __restrict__ W2,
    float* __restrict__ P, int K, int N, int dps)
{
    const int j2 = blockIdx.x*256 + threadIdx.x;
    const int s = blockIdx.y;
    float acc0[32], acc1[32];
    #pragma unroll
    for (int b=0;b<32;++b){ acc0[b]=0.f; acc1[b]=0.f; }
    const int d0 = s*dps, d1 = d0 + dps;
    const int halfN = N >> 1;
    #pragma unroll 2
    for (int d=d0; d<d1; ++d) {
        const float2 wv = W2[(size_t)d*halfN + j2];
        const float* __restrict__ Ad = At + d*32;   // contiguous 128B, wave-uniform -> s_load
        #pragma unroll
        for (int b=0;b<32;++b) {
            const float av = Ad[b];
            acc0[b] = fmaf(av, wv.x, acc0[b]);
            acc1[b] = fmaf(av, wv.y, acc1[b]);
        }
    }
    float* Pp = P + (size_t)(s*32)*N + 2*j2;
    #pragma unroll
    for (int b=0;b<32;++b)
        *reinterpret_cast<float2*>(Pp + (size_t)b*N) = make_float2(acc0[b], acc1[b]);
}

// ---------------- K2: reduce partials + RoPE + pack q/k/v (partner via LDS) ----------------
__global__ __launch_bounds__(256) void qkv_finish(
    const float* __restrict__ P, const float* __restrict__ cosc,
    const float* __restrict__ sinc, const int* __restrict__ spp,
    float* __restrict__ qws, float* __restrict__ kn, float* __restrict__ vn,
    int splits)
{
    __shared__ float sh[256];
    const int t = threadIdx.x;
    const int col = blockIdx.x*256 + t;
    const int b = blockIdx.y;
    float v = 0.f;
    for (int s=0;s<splits;++s) v += P[(size_t)(s*32+b)*6144 + col];
    sh[t] = v;
    __syncthreads();
    if (col < 5120) {
        const int d = col & 127;
        const int pt = (t & ~127) | ((d<64)? d+64 : d-64);
        const float pv = sh[pt];
        const int spos = *spp;
        const float c  = cosc[spos*128 + d];
        const float sn = sinc[spos*128 + d];
        const float rot = (d<64)? -pv : pv;
        const float val = fmaf(v, c, rot*sn);
        if (col < 4096) qws[(size_t)b*4096 + col] = val;
        else            kn[(size_t)b*1024 + (col-4096)] = val;
    } else {
        vn[(size_t)b*1024 + (col-5120)] = v;
    }
}

// ---------------- K4: fused attention; per-wave {scores+mask+max -> fixed-max PV(float4)}, 1 barrier ----------------
__global__ __launch_bounds__(1024, 4) void attn_kernel(
    const float* __restrict__ qws, const float* __restrict__ Kc,
    const float* __restrict__ Vc, const float* __restrict__ kn,
    const float* __restrict__ vn, const float* __restrict__ mask,
    const int* __restrict__ curp, float* __restrict__ aout_t,
    const int PL, const int SW)
{
    __shared__ float scoresS[4*4100];     // 64.1 KB scaled+masked scores [h][p]
    __shared__ float obuf[16][4][128];    // 32 KB unnormalized per-wave O
    __shared__ float redm[16][4];         // per-wave max
    __shared__ float reds[16][4];         // per-wave exp-sum

    const int t = threadIdx.x;
    const int lane = t & 63;
    const int w = t >> 6;
    const int b  = blockIdx.x >> 3;
    const int kv = blockIdx.x & 7;
    const int cur = *curp;

    const size_t mat = (size_t)(b*8+kv);
    const float* __restrict__ Kb  = Kc + mat*(size_t)SW*128;
    const float* __restrict__ knr = kn + mat*128;
    const float* __restrict__ qbase = qws + (size_t)(b*32 + kv*4)*128;

    const float scale = 0.08838834764831845f; // 1/sqrt(128)
    const size_t mbase = ((size_t)b*32 + (size_t)kv*4)*(size_t)PL;

    // ---- Phase A: cooperative QK^T over wave's own chunk; scale+mask+max folded into write ----
    const int l   = lane & 15;
    const int grp = lane >> 4;
    float qv[4][8];
    #pragma unroll
    for (int h=0;h<4;++h)
        #pragma unroll
        for (int j=0;j<8;++j)
            qv[h][j] = qbase[h*128 + l*8 + j];

    const int rpw = PL >> 4;           // rows per wave (252)
    const int rb0 = w * rpw;
    float mA = -3.0e38f;               // running max (meaningful on lanes with l<4)
    for (int g=0; g<rpw; g+=4) {
        const int r = rb0 + g + grp;
        const float* __restrict__ row = (r==cur) ? knr : (Kb + (size_t)r*128);
        const float4 ka = *reinterpret_cast<const float4*>(row + l*8);
        const float4 kb4 = *reinterpret_cast<const float4*>(row + l*8 + 4);
        float kf[8];
        kf[0]=ka.x; kf[1]=ka.y; kf[2]=ka.z; kf[3]=ka.w;
        kf[4]=kb4.x; kf[5]=kb4.y; kf[6]=kb4.z; kf[7]=kb4.w;
        float sc0=0.f, sc1=0.f, sc2=0.f, sc3=0.f;
        #pragma unroll
        for (int j=0;j<8;++j) {
            sc0 = fmaf(qv[0][j], kf[j], sc0);
            sc1 = fmaf(qv[1][j], kf[j], sc1);
            sc2 = fmaf(qv[2][j], kf[j], sc2);
            sc3 = fmaf(qv[3][j], kf[j], sc3);
        }
        #pragma unroll
        for (int off=8; off; off>>=1) {
            sc0 += __shfl_xor(sc0, off, 16);
            sc1 += __shfl_xor(sc1, off, 16);
            sc2 += __shfl_xor(sc2, off, 16);
            sc3 += __shfl_xor(sc3, off, 16);
        }
        if (l < 4) {
            const float v = (l==0)?sc0:(l==1)?sc1:(l==2)?sc2:sc3;
            const float mv = mask[mbase + (size_t)l*PL + r];
            const float sv = fmaf(v, scale, mv);
            scoresS[l*4100 + r] = sv;
            mA = fmaxf(mA, sv);
        }
    }
    // cross-group max combine: lanes 0..3 end with full-wave max for h=0..3
    mA = fmaxf(mA, __shfl_xor(mA, 16, 64));
    mA = fmaxf(mA, __shfl_xor(mA, 32, 64));
    const float m0 = __shfl(mA, 0, 64);
    const float m1 = __shfl(mA, 1, 64);
    const float m2 = __shfl(mA, 2, 64);
    const float m3 = __shfl(mA, 3, 64);
    // No barrier: wave consumes only the chunk it wrote (same-wave DS ordering).

    // ---- PV with fixed per-wave max; float4 V loads, 2 positions per wave-instruction ----
    const float* __restrict__ Vb  = Vc + mat*(size_t)SW*128;
    const float* __restrict__ vnr = vn + mat*128;
    const int dl = lane & 31;          // d-quad: d = 4*dl .. 4*dl+3
    const int pr = lane >> 5;          // position parity
    const int p0 = rb0, p1 = rb0 + rpw;   // rpw even
    float l0=0.f, l1=0.f, l2=0.f, l3=0.f;
    float4 A0 = make_float4(0.f,0.f,0.f,0.f);
    float4 A1 = make_float4(0.f,0.f,0.f,0.f);
    float4 A2 = make_float4(0.f,0.f,0.f,0.f);
    float4 A3 = make_float4(0.f,0.f,0.f,0.f);
    #pragma unroll 4
    for (int p=p0; p<p1; p+=2) {
        const int pp = p + pr;
        const float* row = (pp==cur) ? vnr : (Vb + (size_t)pp*128);
        const float4 vv = *reinterpret_cast<const float4*>(row + 4*dl);
        const float e0 = __expf(scoresS[         pp] - m0);
        const float e1 = __expf(scoresS[ 4100 +  pp] - m1);
        const float e2 = __expf(scoresS[ 8200 +  pp] - m2);
        const float e3 = __expf(scoresS[12300 +  pp] - m3);
        l0 += e0; l1 += e1; l2 += e2; l3 += e3;
        A0.x=fmaf(e0,vv.x,A0.x); A0.y=fmaf(e0,vv.y,A0.y); A0.z=fmaf(e0,vv.z,A0.z); A0.w=fmaf(e0,vv.w,A0.w);
        A1.x=fmaf(e1,vv.x,A1.x); A1.y=fmaf(e1,vv.y,A1.y); A1.z=fmaf(e1,vv.z,A1.z); A1.w=fmaf(e1,vv.w,A1.w);
        A2.x=fmaf(e2,vv.x,A2.x); A2.y=fmaf(e2,vv.y,A2.y); A2.z=fmaf(e2,vv.z,A2.z); A2.w=fmaf(e2,vv.w,A2.w);
        A3.x=fmaf(e3,vv.x,A3.x); A3.y=fmaf(e3,vv.y,A3.y); A3.z=fmaf(e3,vv.z,A3.z); A3.w=fmaf(e3,vv.w,A3.w);
    }
    // merge position parity (lane <-> lane^32)
    A0.x+=__shfl_xor(A0.x,32,64); A0.y+=__shfl_xor(A0.y,32,64); A0.z+=__shfl_xor(A0.z,32,64); A0.w+=__shfl_xor(A0.w,32,64);
    A1.x+=__shfl_xor(A1.x,32,64); A1.y+=__shfl_xor(A1.y,32,64); A1.z+=__shfl_xor(A1.z,32,64); A1.w+=__shfl_xor(A1.w,32,64);
    A2.x+=__shfl_xor(A2.x,32,64); A2.y+=__shfl_xor(A2.y,32,64); A2.z+=__shfl_xor(A2.z,32,64); A2.w+=__shfl_xor(A2.w,32,64);
    A3.x+=__shfl_xor(A3.x,32,64); A3.y+=__shfl_xor(A3.y,32,64); A3.z+=__shfl_xor(A3.z,32,64); A3.w+=__shfl_xor(A3.w,32,64);
    l0 += __shfl_xor(l0,32,64); l1 += __shfl_xor(l1,32,64);
    l2 += __shfl_xor(l2,32,64); l3 += __shfl_xor(l3,32,64);

    if (lane==0) {
        redm[w][0]=m0; redm[w][1]=m1; redm[w][2]=m2; redm[w][3]=m3;
        reds[w][0]=l0; reds[w][1]=l1; reds[w][2]=l2; reds[w][3]=l3;
    }
    if (pr==0) {
        *reinterpret_cast<float4*>(&obuf[w][0][4*dl]) = A0;
        *reinterpret_cast<float4*>(&obuf[w][1][4*dl]) = A1;
        *reinterpret_cast<float4*>(&obuf[w][2][4*dl]) = A2;
        *reinterpret_cast<float4*>(&obuf[w][3][4*dl]) = A3;
    }
    __syncthreads();

    // ---- flash combine across 16 waves + TRANSPOSED writeout ----
    if (t < 512) {
        const int h = t >> 7;
        const int d = t & 127;
        float M = redm[0][h];
        #pragma unroll
        for (int ww=1;ww<16;++ww) M = fmaxf(M, redm[ww][h]);
        float num = 0.f, den = 0.f;
        #pragma unroll
        for (int ww=0;ww<16;++ww) {
            const float f = __expf(redm[ww][h] - M);
            num = fmaf(f, obuf[ww][h][d], num);
            den = fmaf(f, reds[ww][h], den);
        }
        const int col = (kv*4 + h)*128 + d;
        aout_t[(size_t)col*32 + b] = num/den;
    }
}

// ---------------- K5: reduce wo partials -> f32 output ----------------
__global__ __launch_bounds__(256) void wo_finish(
    const float* __restrict__ P, float* __restrict__ out, int splits)
{
    const int col = blockIdx.x*256 + threadIdx.x;
    const int b = blockIdx.y;
    float v = 0.f;
    for (int s=0;s<splits;++s) v += P[(size_t)(s*32+b)*4096 + col];
    out[(size_t)b*4096 + col] = v;
}

extern "C" void kernel_launch(void* const* d_in, const int* in_sizes, int n_in,
                              void* d_out, int out_size, void* d_ws, size_t ws_size,
                              hipStream_t stream)
{
    const float* x    = (const float*)d_in[0];
    const float* wqkv = (const float*)d_in[1];
    const float* wo   = (const float*)d_in[2];
    const float* cK   = (const float*)d_in[3];
    const float* cV   = (const float*)d_in[4];
    const float* cosc = (const float*)d_in[5];
    const float* sinc = (const float*)d_in[6];
    const float* mask = (const float*)d_in[7];
    const int* sp   = (const int*)d_in[8];
    const int* cp   = (const int*)d_in[9];

    const int PL = in_sizes[7] / (32*32);          // padded_len (4032)
    const int SW = in_sizes[3] / (32*8*128);       // cache rows (4096)

    char* ws = (char*)d_ws;
    float* xt    = (float*)(ws);                         // 512 KB
    float* qws   = (float*)(ws + 524288);                // 512 KB
    float* aout_t= (float*)(ws + 2*524288);              // 512 KB
    float* kn    = (float*)(ws + 3*524288);              // 128 KB
    float* vn    = (float*)(ws + 3*524288 + 131072);     // 128 KB
    float* Pbuf  = (float*)(ws + 3*524288 + 2*131072);   // split-K partials (50.3 MB @ splits=64)

    const int splits = 64;
    const int dps = 4096 / splits;                       // 64

    transpose_x<<<64, 256, 0, stream>>>(x, xt);
    gemm_splitk_t<<<dim3(12, splits), 256, 0, stream>>>(xt, (const float2*)wqkv, Pbuf, 4096, 6144, dps);
    qkv_finish<<<dim3(24, 32), 256, 0, stream>>>(Pbuf, cosc, sinc, sp, qws, kn, vn, splits);

    attn_kernel<<<256, 1024, 0, stream>>>(qws, cK, cV, kn, vn, mask, cp, aout_t, PL, SW);

    gemm_splitk_t<<<dim3(8, splits), 256, 0, stream>>>(aout_t, (const float2*)wo, Pbuf, 4096, 4096, dps);
    wo_finish<<<dim3(16, 32), 256, 0, stream>>>(Pbuf, (float*)d_out, splits);
}

// Round 16
// 300.238 us; speedup vs baseline: 1.0478x; 1.0478x over previous
//
#include <hip/hip_runtime.h>
#include <hip/hip_bf16.h>

typedef unsigned int u32;
typedef unsigned short u16;

__device__ __forceinline__ u16 f2bf(float f){ u32 x; __builtin_memcpy(&x,&f,4); u32 r=(x+0x7fffu+((x>>16)&1u))>>16; return (u16)r; }

// ---------------- K0: transpose x (32 x 4096) -> xt (4096 x 32) ----------------
__global__ __launch_bounds__(256) void transpose_x(
    const float* __restrict__ x, float* __restrict__ xt)
{
    __shared__ float ld[32][65];
    const int t = threadIdx.x;
    const int g = blockIdx.x;
    #pragma unroll
    for (int i=0;i<8;++i) {
        const int e = i*256 + t;
        const int b = e >> 6, dd = e & 63;
        ld[b][dd] = x[(size_t)b*4096 + g*64 + dd];
    }
    __syncthreads();
    #pragma unroll
    for (int i=0;i<8;++i) {
        const int e = i*256 + t;
        const int dd = e >> 5, b = e & 31;
        xt[(size_t)(g*64 + dd)*32 + b] = ld[b][dd];
    }
}

// ---------------- K1/K3: split-K GEMM with transposed A: (K x 32) ----------------
__global__ __launch_bounds__(256) void gemm_splitk_t(
    const float* __restrict__ At, const float2* __restrict__ W2,
    float* __restrict__ P, int K, int N, int dps)
{
    const int j2 = blockIdx.x*256 + threadIdx.x;
    const int s = blockIdx.y;
    float acc0[32], acc1[32];
    #pragma unroll
    for (int b=0;b<32;++b){ acc0[b]=0.f; acc1[b]=0.f; }
    const int d0 = s*dps, d1 = d0 + dps;
    const int halfN = N >> 1;
    #pragma unroll 2
    for (int d=d0; d<d1; ++d) {
        const float2 wv = W2[(size_t)d*halfN + j2];
        const float* __restrict__ Ad = At + d*32;   // contiguous 128B, wave-uniform -> s_load
        #pragma unroll
        for (int b=0;b<32;++b) {
            const float av = Ad[b];
            acc0[b] = fmaf(av, wv.x, acc0[b]);
            acc1[b] = fmaf(av, wv.y, acc1[b]);
        }
    }
    float* Pp = P + (size_t)(s*32)*N + 2*j2;
    #pragma unroll
    for (int b=0;b<32;++b)
        *reinterpret_cast<float2*>(Pp + (size_t)b*N) = make_float2(acc0[b], acc1[b]);
}

// ---------------- K2: reduce partials + RoPE + pack q/k/v (partner via LDS) ----------------
__global__ __launch_bounds__(256) void qkv_finish(
    const float* __restrict__ P, const float* __restrict__ cosc,
    const float* __restrict__ sinc, const int* __restrict__ spp,
    float* __restrict__ qws, float* __restrict__ kn, float* __restrict__ vn,
    int splits)
{
    __shared__ float sh[256];
    const int t = threadIdx.x;
    const int col = blockIdx.x*256 + t;
    const int b = blockIdx.y;
    float v = 0.f;
    for (int s=0;s<splits;++s) v += P[(size_t)(s*32+b)*6144 + col];
    sh[t] = v;
    __syncthreads();
    if (col < 5120) {
        const int d = col & 127;
        const int pt = (t & ~127) | ((d<64)? d+64 : d-64);
        const float pv = sh[pt];
        const int spos = *spp;
        const float c  = cosc[spos*128 + d];
        const float sn = sinc[spos*128 + d];
        const float rot = (d<64)? -pv : pv;
        const float val = fmaf(v, c, rot*sn);
        if (col < 4096) qws[(size_t)b*4096 + col] = val;
        else            kn[(size_t)b*1024 + (col-4096)] = val;
    } else {
        vn[(size_t)b*1024 + (col-5120)] = v;
    }
}

// ---------------- K4: fused attention; per-wave {scores -> max-pass -> fixed-max PV}, 1 barrier ----------------
__global__ __launch_bounds__(1024, 4) void attn_kernel(
    const float* __restrict__ qws, const float* __restrict__ Kc,
    const float* __restrict__ Vc, const float* __restrict__ kn,
    const float* __restrict__ vn, const float* __restrict__ mask,
    const int* __restrict__ curp, float* __restrict__ aout_t,
    const int PL, const int SW)
{
    __shared__ float scoresS[4*4100];     // 64.1 KB scores [h][p]; scaled+masked in place
    __shared__ float obuf[16][4][128];    // 32 KB unnormalized per-wave O
    __shared__ float redm[16][4];         // per-wave max
    __shared__ float reds[16][4];         // per-wave exp-sum

    const int t = threadIdx.x;
    const int lane = t & 63;
    const int w = t >> 6;
    const int b  = blockIdx.x >> 3;
    const int kv = blockIdx.x & 7;
    const int cur = *curp;

    const size_t mat = (size_t)(b*8+kv);
    const float* __restrict__ Kb  = Kc + mat*(size_t)SW*128;
    const float* __restrict__ knr = kn + mat*128;
    const float* __restrict__ qbase = qws + (size_t)(b*32 + kv*4)*128;

    // ---- Phase A: cooperative QK^T over wave's own chunk [w*rpw, (w+1)*rpw) ----
    const int l   = lane & 15;
    const int grp = lane >> 4;
    float qv[4][8];
    #pragma unroll
    for (int h=0;h<4;++h)
        #pragma unroll
        for (int j=0;j<8;++j)
            qv[h][j] = qbase[h*128 + l*8 + j];

    const int rpw = PL >> 4;           // rows per wave (252)
    const int rb0 = w * rpw;
    for (int g=0; g<rpw; g+=4) {
        const int r = rb0 + g + grp;
        const float* __restrict__ row = (r==cur) ? knr : (Kb + (size_t)r*128);
        const float4 ka = *reinterpret_cast<const float4*>(row + l*8);
        const float4 kb4 = *reinterpret_cast<const float4*>(row + l*8 + 4);
        float kf[8];
        kf[0]=ka.x; kf[1]=ka.y; kf[2]=ka.z; kf[3]=ka.w;
        kf[4]=kb4.x; kf[5]=kb4.y; kf[6]=kb4.z; kf[7]=kb4.w;
        float sc0=0.f, sc1=0.f, sc2=0.f, sc3=0.f;
        #pragma unroll
        for (int j=0;j<8;++j) {
            sc0 = fmaf(qv[0][j], kf[j], sc0);
            sc1 = fmaf(qv[1][j], kf[j], sc1);
            sc2 = fmaf(qv[2][j], kf[j], sc2);
            sc3 = fmaf(qv[3][j], kf[j], sc3);
        }
        #pragma unroll
        for (int off=8; off; off>>=1) {
            sc0 += __shfl_xor(sc0, off, 16);
            sc1 += __shfl_xor(sc1, off, 16);
            sc2 += __shfl_xor(sc2, off, 16);
            sc3 += __shfl_xor(sc3, off, 16);
        }
        if (l < 4) {
            const float v = (l==0)?sc0:(l==1)?sc1:(l==2)?sc2:sc3;
            scoresS[l*4100 + r] = v;
        }
    }
    // No barrier: wave w wrote exactly the chunk it now consumes (same-wave DS ordering).

    // ---- Max pass: scale+mask in place over own chunk, per-wave max ----
    const float scale = 0.08838834764831845f; // 1/sqrt(128)
    const size_t mbase = ((size_t)b*32 + (size_t)kv*4)*(size_t)PL;
    const int p0 = rb0, p1 = rb0 + rpw;
    float m0=-3.0e38f, m1=-3.0e38f, m2=-3.0e38f, m3=-3.0e38f;
    for (int p = p0 + lane; p < p1; p += 64) {
        const float s0 = fmaf(scoresS[         p], scale, mask[mbase                + p]);
        const float s1 = fmaf(scoresS[ 4100 +  p], scale, mask[mbase +   (size_t)PL + p]);
        const float s2 = fmaf(scoresS[ 8200 +  p], scale, mask[mbase + 2*(size_t)PL + p]);
        const float s3 = fmaf(scoresS[12300 +  p], scale, mask[mbase + 3*(size_t)PL + p]);
        scoresS[         p] = s0;
        scoresS[ 4100 +  p] = s1;
        scoresS[ 8200 +  p] = s2;
        scoresS[12300 +  p] = s3;
        m0 = fmaxf(m0, s0); m1 = fmaxf(m1, s1);
        m2 = fmaxf(m2, s2); m3 = fmaxf(m3, s3);
    }
    #pragma unroll
    for (int off=1; off<64; off<<=1) {
        m0 = fmaxf(m0, __shfl_xor(m0, off, 64));
        m1 = fmaxf(m1, __shfl_xor(m1, off, 64));
        m2 = fmaxf(m2, __shfl_xor(m2, off, 64));
        m3 = fmaxf(m3, __shfl_xor(m3, off, 64));
    }

    // ---- PV with fixed per-wave max: e = exp(s - m); l += e; O += e*V ----
    const float* __restrict__ Vb  = Vc + mat*(size_t)SW*128;
    const float* __restrict__ vnr = vn + mat*128;
    float l0=0.f, l1=0.f, l2=0.f, l3=0.f;
    float a0[4] = {0.f,0.f,0.f,0.f}, a1[4] = {0.f,0.f,0.f,0.f};
    #pragma unroll 4
    for (int p=p0; p<p1; ++p) {
        const float* row = (p==cur) ? vnr : (Vb + (size_t)p*128);
        const float2 vv = *reinterpret_cast<const float2*>(row + 2*lane);
        const float e0 = __expf(scoresS[         p] - m0);
        const float e1 = __expf(scoresS[ 4100 +  p] - m1);
        const float e2 = __expf(scoresS[ 8200 +  p] - m2);
        const float e3 = __expf(scoresS[12300 +  p] - m3);
        l0 += e0; l1 += e1; l2 += e2; l3 += e3;
        a0[0] = fmaf(e0, vv.x, a0[0]); a1[0] = fmaf(e0, vv.y, a1[0]);
        a0[1] = fmaf(e1, vv.x, a0[1]); a1[1] = fmaf(e1, vv.y, a1[1]);
        a0[2] = fmaf(e2, vv.x, a0[2]); a1[2] = fmaf(e2, vv.y, a1[2]);
        a0[3] = fmaf(e3, vv.x, a0[3]); a1[3] = fmaf(e3, vv.y, a1[3]);
    }

    if (lane==0) {
        redm[w][0]=m0; redm[w][1]=m1; redm[w][2]=m2; redm[w][3]=m3;
        reds[w][0]=l0; reds[w][1]=l1; reds[w][2]=l2; reds[w][3]=l3;
    }
    #pragma unroll
    for (int h=0;h<4;++h)
        *reinterpret_cast<float2*>(&obuf[w][h][2*lane]) = make_float2(a0[h], a1[h]);
    __syncthreads();

    // ---- flash combine across 16 waves + TRANSPOSED writeout ----
    if (t < 512) {
        const int h = t >> 7;
        const int d = t & 127;
        float M = redm[0][h];
        #pragma unroll
        for (int ww=1;ww<16;++ww) M = fmaxf(M, redm[ww][h]);
        float num = 0.f, den = 0.f;
        #pragma unroll
        for (int ww=0;ww<16;++ww) {
            const float f = __expf(redm[ww][h] - M);
            num = fmaf(f, obuf[ww][h][d], num);
            den = fmaf(f, reds[ww][h], den);
        }
        const int col = (kv*4 + h)*128 + d;
        aout_t[(size_t)col*32 + b] = num/den;
    }
}

// ---------------- K5: reduce wo partials -> f32 output ----------------
__global__ __launch_bounds__(256) void wo_finish(
    const float* __restrict__ P, float* __restrict__ out, int splits)
{
    const int col = blockIdx.x*256 + threadIdx.x;
    const int b = blockIdx.y;
    float v = 0.f;
    for (int s=0;s<splits;++s) v += P[(size_t)(s*32+b)*4096 + col];
    out[(size_t)b*4096 + col] = v;
}

extern "C" void kernel_launch(void* const* d_in, const int* in_sizes, int n_in,
                              void* d_out, int out_size, void* d_ws, size_t ws_size,
                              hipStream_t stream)
{
    const float* x    = (const float*)d_in[0];
    const float* wqkv = (const float*)d_in[1];
    const float* wo   = (const float*)d_in[2];
    const float* cK   = (const float*)d_in[3];
    const float* cV   = (const float*)d_in[4];
    const float* cosc = (const float*)d_in[5];
    const float* sinc = (const float*)d_in[6];
    const float* mask = (const float*)d_in[7];
    const int* sp   = (const int*)d_in[8];
    const int* cp   = (const int*)d_in[9];

    const int PL = in_sizes[7] / (32*32);          // padded_len (4032)
    const int SW = in_sizes[3] / (32*8*128);       // cache rows (4096)

    char* ws = (char*)d_ws;
    float* xt    = (float*)(ws);                         // 512 KB
    float* qws   = (float*)(ws + 524288);                // 512 KB
    float* aout_t= (float*)(ws + 2*524288);              // 512 KB
    float* kn    = (float*)(ws + 3*524288);              // 128 KB
    float* vn    = (float*)(ws + 3*524288 + 131072);     // 128 KB
    float* Pbuf  = (float*)(ws + 3*524288 + 2*131072);   // split-K partials (50.3 MB @ splits=64)

    const int splits = 64;
    const int dps = 4096 / splits;                       // 64

    transpose_x<<<64, 256, 0, stream>>>(x, xt);
    gemm_splitk_t<<<dim3(12, splits), 256, 0, stream>>>(xt, (const float2*)wqkv, Pbuf, 4096, 6144, dps);
    qkv_finish<<<dim3(24, 32), 256, 0, stream>>>(Pbuf, cosc, sinc, sp, qws, kn, vn, splits);

    attn_kernel<<<256, 1024, 0, stream>>>(qws, cK, cV, kn, vn, mask, cp, aout_t, PL, SW);

    gemm_splitk_t<<<dim3(8, splits), 256, 0, stream>>>(aout_t, (const float2*)wo, Pbuf, 4096, 4096, dps);
    wo_finish<<<dim3(16, 32), 256, 0, stream>>>(Pbuf, (float*)d_out, splits);
}